// Round 2
// baseline (2892.039 us; speedup 1.0000x reference)
//
#include <hip/hip_runtime.h>
#include <math.h>

// MoE MLP (top-2 of 8 experts), T=4096 tokens, H=1024, FF=4096, fp32.
// Gathered (token-routed) implementation: only selected (token,expert) pairs
// are computed (1.37e11 FLOPs vs 5.5e11 dense). Zeroed-out experts in the
// reference contribute exactly 0, so skipping them is exact.

#define T_TOK 4096
#define H_DIM 1024
#define FF_DIM 4096
#define NE 8
#define CAP 4096          // per-expert token capacity (worst case all tokens)

#define BM 128
#define BN 128
#define BK 16
#define AST (BM + 4)      // padded LDS stride for k-major A tile

__device__ __forceinline__ float gelu_tanh(float v) {
    // jax.nn.gelu default (approximate=True, tanh form)
    const float c = 0.7978845608028654f;
    float u = c * (v + 0.044715f * v * v * v);
    return 0.5f * v * (1.0f + tanhf(u));
}

// ---------------- router: logits, top-2 softmax, routing lists, aux accum ---
__global__ __launch_bounds__(64) void router_kernel(
    const float* __restrict__ x, const float* __restrict__ Wg,
    float* __restrict__ out_rl, int* __restrict__ counts,
    int* __restrict__ toklist, float* __restrict__ wtlist,
    double* __restrict__ accp, double* __restrict__ zsum)
{
    int t = blockIdx.x;
    int lane = threadIdx.x;
    float acc[NE];
#pragma unroll
    for (int e = 0; e < NE; ++e) acc[e] = 0.f;
    const float* xr = x + (size_t)t * H_DIM;
    for (int h = lane; h < H_DIM; h += 64) {
        float xv = xr[h];
        const float4* wr = (const float4*)(Wg + (size_t)h * NE);
        float4 w0 = wr[0], w1 = wr[1];
        acc[0] += xv * w0.x; acc[1] += xv * w0.y;
        acc[2] += xv * w0.z; acc[3] += xv * w0.w;
        acc[4] += xv * w1.x; acc[5] += xv * w1.y;
        acc[6] += xv * w1.z; acc[7] += xv * w1.w;
    }
#pragma unroll
    for (int e = 0; e < NE; ++e) {
#pragma unroll
        for (int off = 32; off; off >>= 1) acc[e] += __shfl_xor(acc[e], off, 64);
    }
    if (lane != 0) return;

    // router_logits output
    float4* op = (float4*)(out_rl + (size_t)t * NE);
    op[0] = make_float4(acc[0], acc[1], acc[2], acc[3]);
    op[1] = make_float4(acc[4], acc[5], acc[6], acc[7]);

    // top-2 (lowest index wins ties, matching lax.top_k)
    int i0 = 0; float v0 = acc[0];
#pragma unroll
    for (int e = 1; e < NE; ++e) { if (acc[e] > v0) { v0 = acc[e]; i0 = e; } }
    int i1 = -1; float v1 = -3.4e38f;
#pragma unroll
    for (int e = 0; e < NE; ++e) {
        if (e == i0) continue;
        if (acc[e] > v1) { v1 = acc[e]; i1 = e; }
    }
    float ed = expf(v1 - v0);
    float rw0 = 1.f / (1.f + ed);
    float rw1 = ed / (1.f + ed);

    // full softmax for acc_probs; logsumexp for z-loss
    float s = 0.f, p[NE];
#pragma unroll
    for (int e = 0; e < NE; ++e) { p[e] = expf(acc[e] - v0); s += p[e]; }
    float inv = 1.f / s;
#pragma unroll
    for (int e = 0; e < NE; ++e) atomicAdd(&accp[e], (double)(p[e] * inv));
    float lse = v0 + logf(s);
    atomicAdd(zsum, (double)lse * (double)lse);

    // routing lists (freq[e] == counts[e] since top-2 indices are distinct)
    int pos0 = atomicAdd(&counts[i0], 1);
    toklist[i0 * CAP + pos0] = t; wtlist[i0 * CAP + pos0] = rw0;
    int pos1 = atomicAdd(&counts[i1], 1);
    toklist[i1 * CAP + pos1] = t; wtlist[i1 * CAP + pos1] = rw1;
}

// ---------------- finalize: compact offsets + aux loss ----------------------
__global__ void finalize_kernel(const int* __restrict__ counts, int* __restrict__ offsets,
                                const double* __restrict__ accp, const double* __restrict__ zsum,
                                float* __restrict__ out_aux)
{
    if (threadIdx.x == 0 && blockIdx.x == 0) {
        int off = 0;
        double psum = 0.0, sw = 0.0;
        int c[NE];
        for (int e = 0; e < NE; ++e) {
            c[e] = counts[e]; offsets[e] = off; off += c[e]; psum += accp[e];
        }
        for (int e = 0; e < NE; ++e)
            sw += (accp[e] / psum) * ((double)c[e] / (double)(T_TOK * 2));
        sw *= (double)NE;
        double z = zsum[0] / (double)T_TOK;
        out_aux[0] = (float)(sw + 0.1 * z);
    }
}

// ---------------- GEMM1: Hbuf = gelu(gather(x) @ W1[e]) ---------------------
__global__ __launch_bounds__(256) void gemm1_kernel(
    const float* __restrict__ x, const float* __restrict__ W1,
    const int* __restrict__ counts, const int* __restrict__ offsets,
    const int* __restrict__ toklist, float* __restrict__ Hbuf,
    int ff0, int chunk_ff)
{
    int e = blockIdx.z;
    int cnt = counts[e];
    int row0 = blockIdx.y * BM;
    if (row0 >= cnt) return;

    __shared__ float As[BK][AST];   // k-major gathered x tile
    __shared__ float Bs[BK][BN];
    __shared__ int stok[BM];

    int tid = threadIdx.x;
    if (tid < BM) {
        int r = row0 + tid;
        stok[tid] = (r < cnt) ? toklist[e * CAP + r] : -1;
    }
    __syncthreads();

    int arow = tid >> 1;            // 0..127
    int akk  = (tid & 1) * 8;       // 0 or 8
    int tokA = stok[arow];
    bool avalid = tokA >= 0;
    const float* aptr = x + (size_t)(avalid ? tokA : 0) * H_DIM + akk;

    int bkk = tid >> 4;             // 0..15
    int bn  = (tid & 15) * 8;       // 0..120
    const float* bptr = W1 + (size_t)e * H_DIM * FF_DIM
                           + (size_t)bkk * FF_DIM + (ff0 + blockIdx.x * BN) + bn;

    int tx = tid & 15, ty = tid >> 4;
    float accr[8][8];
#pragma unroll
    for (int i = 0; i < 8; ++i)
#pragma unroll
        for (int j = 0; j < 8; ++j) accr[i][j] = 0.f;

    for (int k0 = 0; k0 < H_DIM; k0 += BK) {
        float4 a0 = make_float4(0.f, 0.f, 0.f, 0.f), a1 = a0;
        if (avalid) {
            a0 = *(const float4*)(aptr + k0);
            a1 = *(const float4*)(aptr + k0 + 4);
        }
        float4 b0 = *(const float4*)(bptr);
        float4 b1 = *(const float4*)(bptr + 4);
        bptr += (size_t)BK * FF_DIM;
        __syncthreads();
        As[akk + 0][arow] = a0.x; As[akk + 1][arow] = a0.y;
        As[akk + 2][arow] = a0.z; As[akk + 3][arow] = a0.w;
        As[akk + 4][arow] = a1.x; As[akk + 5][arow] = a1.y;
        As[akk + 6][arow] = a1.z; As[akk + 7][arow] = a1.w;
        *(float4*)&Bs[bkk][bn]     = b0;
        *(float4*)&Bs[bkk][bn + 4] = b1;
        __syncthreads();
#pragma unroll
        for (int kk = 0; kk < BK; ++kk) {
            float av[8], bv[8];
            *(float4*)&av[0] = *(const float4*)&As[kk][ty * 8];
            *(float4*)&av[4] = *(const float4*)&As[kk][ty * 8 + 4];
            *(float4*)&bv[0] = *(const float4*)&Bs[kk][tx * 8];
            *(float4*)&bv[4] = *(const float4*)&Bs[kk][tx * 8 + 4];
#pragma unroll
            for (int i = 0; i < 8; ++i)
#pragma unroll
                for (int j = 0; j < 8; ++j)
                    accr[i][j] = fmaf(av[i], bv[j], accr[i][j]);
        }
    }

    int obase = offsets[e];
    int ncol = blockIdx.x * BN + tx * 8;   // chunk-local column
#pragma unroll
    for (int i = 0; i < 8; ++i) {
        int r = row0 + ty * 8 + i;
        if (r < cnt) {
            float* orow = Hbuf + (size_t)(obase + r) * chunk_ff + ncol;
            *(float4*)(orow) = make_float4(gelu_tanh(accr[i][0]), gelu_tanh(accr[i][1]),
                                           gelu_tanh(accr[i][2]), gelu_tanh(accr[i][3]));
            *(float4*)(orow + 4) = make_float4(gelu_tanh(accr[i][4]), gelu_tanh(accr[i][5]),
                                               gelu_tanh(accr[i][6]), gelu_tanh(accr[i][7]));
        }
    }
}

// ---------------- GEMM2: out += w * (Hbuf @ W2[e]) (scatter) ----------------
__global__ __launch_bounds__(256) void gemm2_kernel(
    const float* __restrict__ Hbuf, const float* __restrict__ W2,
    const int* __restrict__ counts, const int* __restrict__ offsets,
    const int* __restrict__ toklist, const float* __restrict__ wtlist,
    float* __restrict__ out, int ff0, int chunk_ff)
{
    int e = blockIdx.z;
    int cnt = counts[e];
    int row0 = blockIdx.y * BM;
    if (row0 >= cnt) return;

    __shared__ float As[BK][AST];
    __shared__ float Bs[BK][BN];
    __shared__ int   stok[BM];
    __shared__ float swt[BM];

    int tid = threadIdx.x;
    if (tid < BM) {
        int r = row0 + tid;
        stok[tid] = (r < cnt) ? toklist[e * CAP + r] : 0;
        swt[tid]  = (r < cnt) ? wtlist[e * CAP + r] : 0.f;
    }
    __syncthreads();

    int arow = tid >> 1;
    int akk  = (tid & 1) * 8;
    int obase = offsets[e];
    bool avalid = (row0 + arow) < cnt;
    const float* aptr = Hbuf + (size_t)(obase + (avalid ? (row0 + arow) : 0)) * chunk_ff + akk;

    int bkk = tid >> 4;
    int bn  = (tid & 15) * 8;
    int n0 = blockIdx.x * BN;
    const float* bptr = W2 + (size_t)e * FF_DIM * H_DIM
                           + (size_t)(ff0 + bkk) * H_DIM + n0 + bn;

    int tx = tid & 15, ty = tid >> 4;
    float accr[8][8];
#pragma unroll
    for (int i = 0; i < 8; ++i)
#pragma unroll
        for (int j = 0; j < 8; ++j) accr[i][j] = 0.f;

    for (int k0 = 0; k0 < chunk_ff; k0 += BK) {
        float4 a0 = make_float4(0.f, 0.f, 0.f, 0.f), a1 = a0;
        if (avalid) {
            a0 = *(const float4*)(aptr + k0);
            a1 = *(const float4*)(aptr + k0 + 4);
        }
        float4 b0 = *(const float4*)(bptr);
        float4 b1 = *(const float4*)(bptr + 4);
        bptr += (size_t)BK * H_DIM;
        __syncthreads();
        As[akk + 0][arow] = a0.x; As[akk + 1][arow] = a0.y;
        As[akk + 2][arow] = a0.z; As[akk + 3][arow] = a0.w;
        As[akk + 4][arow] = a1.x; As[akk + 5][arow] = a1.y;
        As[akk + 6][arow] = a1.z; As[akk + 7][arow] = a1.w;
        *(float4*)&Bs[bkk][bn]     = b0;
        *(float4*)&Bs[bkk][bn + 4] = b1;
        __syncthreads();
#pragma unroll
        for (int kk = 0; kk < BK; ++kk) {
            float av[8], bv[8];
            *(float4*)&av[0] = *(const float4*)&As[kk][ty * 8];
            *(float4*)&av[4] = *(const float4*)&As[kk][ty * 8 + 4];
            *(float4*)&bv[0] = *(const float4*)&Bs[kk][tx * 8];
            *(float4*)&bv[4] = *(const float4*)&Bs[kk][tx * 8 + 4];
#pragma unroll
            for (int i = 0; i < 8; ++i)
#pragma unroll
                for (int j = 0; j < 8; ++j)
                    accr[i][j] = fmaf(av[i], bv[j], accr[i][j]);
        }
    }

#pragma unroll
    for (int i = 0; i < 8; ++i) {
        int r = row0 + ty * 8 + i;
        if (r < cnt) {
            int   tt = stok[ty * 8 + i];
            float w  = swt[ty * 8 + i];
            float* orow = out + (size_t)tt * H_DIM + n0 + tx * 8;
#pragma unroll
            for (int j = 0; j < 8; ++j)
                atomicAdd(&orow[j], w * accr[i][j]);   // exactly 2 commutative adds/elem
        }
    }
}

// ---------------- launch ----------------------------------------------------
extern "C" void kernel_launch(void* const* d_in, const int* in_sizes, int n_in,
                              void* d_out, int out_size, void* d_ws, size_t ws_size,
                              hipStream_t stream)
{
    const float* x  = (const float*)d_in[0];
    const float* Wg = (const float*)d_in[1];
    const float* W1 = (const float*)d_in[2];
    const float* W2 = (const float*)d_in[3];
    float* out     = (float*)d_out;
    float* out_rl  = out + (size_t)T_TOK * H_DIM;
    float* out_aux = out_rl + (size_t)T_TOK * NE;

    char* ws = (char*)d_ws;
    int*    counts  = (int*)(ws + 0);       // 8 ints   (zeroed)
    double* accp    = (double*)(ws + 64);   // 8 dbl    (zeroed)
    double* zsum    = (double*)(ws + 128);  // 1 dbl    (zeroed)
    int*    offsets = (int*)(ws + 192);     // 8 ints
    int*    toklist = (int*)(ws + 256);                  // 8*4096 ints
    float*  wtlist  = (float*)(ws + 256 + 131072);       // 8*4096 floats
    float*  Hbuf    = (float*)(ws + 262400);             // compact gelu buffer

    // Choose FF chunking so Hbuf fits the workspace (prefer 1 chunk = 134 MB).
    // chunk_ff must stay a multiple of BN(128): nchunks <= 32.
    size_t avail = (ws_size > 262400) ? ws_size - 262400 : 0;
    int nchunks = 1;
    while (nchunks < 32 &&
           (size_t)(T_TOK * 2) * (size_t)(FF_DIM / nchunks) * 4 > avail)
        nchunks *= 2;
    int chunk_ff = FF_DIM / nchunks;

    hipMemsetAsync(d_out, 0, (size_t)T_TOK * H_DIM * sizeof(float), stream);
    hipMemsetAsync(d_ws, 0, 256, stream);

    router_kernel<<<T_TOK, 64, 0, stream>>>(x, Wg, out_rl, counts, toklist, wtlist,
                                            accp, zsum);
    finalize_kernel<<<1, 64, 0, stream>>>(counts, offsets, accp, zsum, out_aux);

    for (int c = 0; c < nchunks; ++c) {
        int ff0 = c * chunk_ff;
        gemm1_kernel<<<dim3(chunk_ff / BN, CAP / BM, NE), 256, 0, stream>>>(
            x, W1, counts, offsets, toklist, Hbuf, ff0, chunk_ff);
        gemm2_kernel<<<dim3(H_DIM / BN, CAP / BM, NE), 256, 0, stream>>>(
            Hbuf, W2, counts, offsets, toklist, wtlist, out, ff0, chunk_ff);
    }
}

// Round 3
// 1031.681 us; speedup vs baseline: 2.8032x; 2.8032x over previous
//
#include <hip/hip_runtime.h>
#include <math.h>

// MoE MLP (top-2 of 8), T=4096, H=1024, FF=4096.
// Round 3 experiment: expert GEMMs on f16 MFMA (router/top-k/aux stay fp32).
// Gathered routing; W1/W2 pre-transposed+converted to k-contiguous f16 per chunk.

#define T_TOK 4096
#define H_DIM 1024
#define FF_DIM 4096
#define NE 8
#define CAP 4096
#define HBUF_ROWS (2 * T_TOK + 128)   // +128 rows slack: staging may read past cnt

typedef _Float16 f16;
typedef _Float16 f16x8 __attribute__((ext_vector_type(8)));
typedef _Float16 f16x4 __attribute__((ext_vector_type(4)));
typedef float    f32x4 __attribute__((ext_vector_type(4)));

__device__ __forceinline__ float gelu_tanh(float v) {
    const float c = 0.7978845608028654f;
    float u = c * (v + 0.044715f * v * v * v);
    return 0.5f * v * (1.0f + tanhf(u));
}

__device__ __forceinline__ void gload16(const void* g, void* l) {
    __builtin_amdgcn_global_load_lds(
        (const __attribute__((address_space(1))) unsigned int*)g,
        (__attribute__((address_space(3))) unsigned int*)l, 16, 0, 0);
}

// ---------------- router (fp32, unchanged from passing baseline) ------------
__global__ __launch_bounds__(64) void router_kernel(
    const float* __restrict__ x, const float* __restrict__ Wg,
    float* __restrict__ out_rl, int* __restrict__ counts,
    int* __restrict__ toklist, float* __restrict__ wtlist,
    double* __restrict__ accp, double* __restrict__ zsum)
{
    int t = blockIdx.x;
    int lane = threadIdx.x;
    float acc[NE];
#pragma unroll
    for (int e = 0; e < NE; ++e) acc[e] = 0.f;
    const float* xr = x + (size_t)t * H_DIM;
    for (int h = lane; h < H_DIM; h += 64) {
        float xv = xr[h];
        const float4* wr = (const float4*)(Wg + (size_t)h * NE);
        float4 w0 = wr[0], w1 = wr[1];
        acc[0] += xv * w0.x; acc[1] += xv * w0.y;
        acc[2] += xv * w0.z; acc[3] += xv * w0.w;
        acc[4] += xv * w1.x; acc[5] += xv * w1.y;
        acc[6] += xv * w1.z; acc[7] += xv * w1.w;
    }
#pragma unroll
    for (int e = 0; e < NE; ++e) {
#pragma unroll
        for (int off = 32; off; off >>= 1) acc[e] += __shfl_xor(acc[e], off, 64);
    }
    if (lane != 0) return;

    float4* op = (float4*)(out_rl + (size_t)t * NE);
    op[0] = make_float4(acc[0], acc[1], acc[2], acc[3]);
    op[1] = make_float4(acc[4], acc[5], acc[6], acc[7]);

    int i0 = 0; float v0 = acc[0];
#pragma unroll
    for (int e = 1; e < NE; ++e) { if (acc[e] > v0) { v0 = acc[e]; i0 = e; } }
    int i1 = -1; float v1 = -3.4e38f;
#pragma unroll
    for (int e = 0; e < NE; ++e) {
        if (e == i0) continue;
        if (acc[e] > v1) { v1 = acc[e]; i1 = e; }
    }
    float ed = expf(v1 - v0);
    float rw0 = 1.f / (1.f + ed);
    float rw1 = ed / (1.f + ed);

    float s = 0.f, p[NE];
#pragma unroll
    for (int e = 0; e < NE; ++e) { p[e] = expf(acc[e] - v0); s += p[e]; }
    float inv = 1.f / s;
#pragma unroll
    for (int e = 0; e < NE; ++e) atomicAdd(&accp[e], (double)(p[e] * inv));
    float lse = v0 + logf(s);
    atomicAdd(zsum, (double)lse * (double)lse);

    int pos0 = atomicAdd(&counts[i0], 1);
    toklist[i0 * CAP + pos0] = t; wtlist[i0 * CAP + pos0] = rw0;
    int pos1 = atomicAdd(&counts[i1], 1);
    toklist[i1 * CAP + pos1] = t; wtlist[i1 * CAP + pos1] = rw1;
}

__global__ void finalize_kernel(const int* __restrict__ counts, int* __restrict__ offsets,
                                const double* __restrict__ accp, const double* __restrict__ zsum,
                                float* __restrict__ out_aux)
{
    if (threadIdx.x == 0 && blockIdx.x == 0) {
        int off = 0;
        double psum = 0.0, sw = 0.0;
        int c[NE];
        for (int e = 0; e < NE; ++e) {
            c[e] = counts[e]; offsets[e] = off; off += c[e]; psum += accp[e];
        }
        for (int e = 0; e < NE; ++e)
            sw += (accp[e] / psum) * ((double)c[e] / (double)(T_TOK * 2));
        sw *= (double)NE;
        double z = zsum[0] / (double)T_TOK;
        out_aux[0] = (float)(sw + 0.1 * z);
    }
}

// ---------------- x -> f16 --------------------------------------------------
__global__ __launch_bounds__(256) void cvt_x_kernel(const float* __restrict__ x,
                                                    f16* __restrict__ xh)
{
    int i = (blockIdx.x * 256 + threadIdx.x) * 8;
    float4 a = *(const float4*)(x + i);
    float4 b = *(const float4*)(x + i + 4);
    f16x8 v = { (f16)a.x, (f16)a.y, (f16)a.z, (f16)a.w,
                (f16)b.x, (f16)b.y, (f16)b.z, (f16)b.w };
    *(f16x8*)(xh + i) = v;
}

// ---------------- fp32 [R][C] -> f16 [C][R] transpose (per expert z) --------
__global__ __launch_bounds__(256) void tr_kernel(
    const float* __restrict__ src, f16* __restrict__ dst,
    int src_ld, int dst_ld, long src_es, long dst_es)
{
    __shared__ f16 t[32 * 33];
    int e = blockIdx.z;
    src += (long)e * src_es; dst += (long)e * dst_es;
    int c0 = blockIdx.x * 32, r0 = blockIdx.y * 32;
    int tid = threadIdx.x;
    int cl = tid & 31, rl = tid >> 5;
#pragma unroll
    for (int i = 0; i < 4; ++i) {
        int r = rl + i * 8;
        t[cl * 33 + r] = (f16)src[(long)(r0 + r) * src_ld + c0 + cl];
    }
    __syncthreads();
    int cs = tid >> 3, r4 = (tid & 7) * 4;
    f16x4 v = { t[cs * 33 + r4], t[cs * 33 + r4 + 1],
                t[cs * 33 + r4 + 2], t[cs * 33 + r4 + 3] };
    *(f16x4*)(dst + (long)(c0 + cs) * dst_ld + r0 + r4) = v;
}

// ---------------- GEMM1: Hbuf = gelu(gather(xh) @ W1t^T) f16 MFMA -----------
// A: gathered xh rows [128 x K=1024], B: W1t rows (n-major, k-contig) [128 x K]
__global__ __launch_bounds__(256) void gemm1_f16_kernel(
    const f16* __restrict__ xh, const f16* __restrict__ W1t,
    const int* __restrict__ counts, const int* __restrict__ offsets,
    const int* __restrict__ toklist, f16* __restrict__ Hbuf, int cf)
{
    int e = blockIdx.z;
    int cnt = counts[e];
    int row0 = blockIdx.y * 128;
    if (row0 >= cnt) return;
    int n0 = blockIdx.x * 128;

    __shared__ f16 lds[16384];           // A: [0,4096) B: [4096,8192); epilogue reuses all
    __shared__ int stok[128];
    f16* Ah = lds;
    f16* Bh = lds + 4096;

    int tid = threadIdx.x;
    if (tid < 128) {
        int r = row0 + tid;
        stok[tid] = (r < cnt) ? toklist[e * CAP + r] : 0;
    }
    __syncthreads();

    int l = tid & 63, w = tid >> 6;
    int wr = w >> 1, wc = w & 1;

    int sr = l >> 2;                 // staged row within 16-row group
    int sk = (l & 3) * 8;            // k offset (halves)
    int aR0 = w * 32 + sr, aR1 = aR0 + 16;
    const f16* aG0 = xh + (long)stok[aR0] * H_DIM + sk;
    const f16* aG1 = xh + (long)stok[aR1] * H_DIM + sk;
    const f16* bG0 = W1t + ((long)e * cf + n0 + aR0) * H_DIM + sk;
    const f16* bG1 = W1t + ((long)e * cf + n0 + aR1) * H_DIM + sk;
    f16* aL = Ah + w * 1024;         // wave-uniform LDS dest bases
    f16* bL = Bh + w * 1024;

    f32x4 acc[4][4];
#pragma unroll
    for (int m = 0; m < 4; ++m)
#pragma unroll
        for (int n = 0; n < 4; ++n) acc[m][n] = (f32x4){0.f, 0.f, 0.f, 0.f};

    int lr = l & 15, lg = l >> 4;
    for (int k0 = 0; k0 < H_DIM; k0 += 32) {
        __syncthreads();
        gload16(aG0 + k0, aL);
        gload16(aG1 + k0, aL + 512);
        gload16(bG0 + k0, bL);
        gload16(bG1 + k0, bL + 512);
        __syncthreads();
        f16x8 af[4], bf[4];
#pragma unroll
        for (int m = 0; m < 4; ++m)
            af[m] = *(const f16x8*)&Ah[(wr * 64 + m * 16 + lr) * 32 + lg * 8];
#pragma unroll
        for (int n = 0; n < 4; ++n)
            bf[n] = *(const f16x8*)&Bh[(wc * 64 + n * 16 + lr) * 32 + lg * 8];
#pragma unroll
        for (int m = 0; m < 4; ++m)
#pragma unroll
            for (int n = 0; n < 4; ++n)
                acc[m][n] = __builtin_amdgcn_mfma_f32_16x16x32_f16(af[m], bf[n], acc[m][n], 0, 0, 0);
    }

    // epilogue: gelu -> f16 via LDS bounce, vectorized stores
    __syncthreads();
    int obase = offsets[e];
    f16* ct = lds + w * 4096;        // 64x64 halves per wave
#pragma unroll
    for (int m = 0; m < 4; ++m)
#pragma unroll
        for (int n = 0; n < 4; ++n)
#pragma unroll
            for (int r = 0; r < 4; ++r)
                ct[(m * 16 + lg * 4 + r) * 64 + n * 16 + lr] = (f16)gelu_tanh(acc[m][n][r]);
#pragma unroll
    for (int i = 0; i < 8; ++i) {
        int rr = i * 8 + (l >> 3);
        int grow = row0 + wr * 64 + rr;
        if (grow < cnt) {
            f16x8 v = *(const f16x8*)&ct[rr * 64 + (l & 7) * 8];
            *(f16x8*)(Hbuf + (long)(obase + grow) * cf + n0 + wc * 64 + (l & 7) * 8) = v;
        }
    }
}

// ---------------- GEMM2: out += w * (Hbuf @ W2t^T), scatter atomics ---------
__global__ __launch_bounds__(256) void gemm2_f16_kernel(
    const f16* __restrict__ Hbuf, const f16* __restrict__ W2t,
    const int* __restrict__ counts, const int* __restrict__ offsets,
    const int* __restrict__ toklist, const float* __restrict__ wtlist,
    float* __restrict__ out, int cf)
{
    int e = blockIdx.z;
    int cnt = counts[e];
    int row0 = blockIdx.y * 128;
    if (row0 >= cnt) return;
    int n0 = blockIdx.x * 128;

    __shared__ f16 lds[8192];            // A: [0,4096) B: [4096,8192)
    __shared__ int   stok[128];
    __shared__ float swt[128];
    f16* Ah = lds;
    f16* Bh = lds + 4096;

    int tid = threadIdx.x;
    if (tid < 128) {
        int r = row0 + tid;
        stok[tid] = (r < cnt) ? toklist[e * CAP + r] : 0;
        swt[tid]  = (r < cnt) ? wtlist[e * CAP + r] : 0.f;
    }
    __syncthreads();

    int l = tid & 63, w = tid >> 6;
    int wr = w >> 1, wc = w & 1;

    int sr = l >> 2;
    int sk = (l & 3) * 8;
    int aR0 = w * 32 + sr, aR1 = aR0 + 16;
    int obase = offsets[e];
    // rows >= cnt read Hbuf slack rows (finite garbage, results discarded)
    const f16* aG0 = Hbuf + (long)(obase + row0 + aR0) * cf + sk;
    const f16* aG1 = Hbuf + (long)(obase + row0 + aR1) * cf + sk;
    const f16* bG0 = W2t + ((long)e * H_DIM + n0 + aR0) * cf + sk;
    const f16* bG1 = W2t + ((long)e * H_DIM + n0 + aR1) * cf + sk;
    f16* aL = Ah + w * 1024;
    f16* bL = Bh + w * 1024;

    f32x4 acc[4][4];
#pragma unroll
    for (int m = 0; m < 4; ++m)
#pragma unroll
        for (int n = 0; n < 4; ++n) acc[m][n] = (f32x4){0.f, 0.f, 0.f, 0.f};

    int lr = l & 15, lg = l >> 4;
    for (int k0 = 0; k0 < cf; k0 += 32) {
        __syncthreads();
        gload16(aG0 + k0, aL);
        gload16(aG1 + k0, aL + 512);
        gload16(bG0 + k0, bL);
        gload16(bG1 + k0, bL + 512);
        __syncthreads();
        f16x8 af[4], bf[4];
#pragma unroll
        for (int m = 0; m < 4; ++m)
            af[m] = *(const f16x8*)&Ah[(wr * 64 + m * 16 + lr) * 32 + lg * 8];
#pragma unroll
        for (int n = 0; n < 4; ++n)
            bf[n] = *(const f16x8*)&Bh[(wc * 64 + n * 16 + lr) * 32 + lg * 8];
#pragma unroll
        for (int m = 0; m < 4; ++m)
#pragma unroll
            for (int n = 0; n < 4; ++n)
                acc[m][n] = __builtin_amdgcn_mfma_f32_16x16x32_f16(af[m], bf[n], acc[m][n], 0, 0, 0);
    }

#pragma unroll
    for (int m = 0; m < 4; ++m)
#pragma unroll
        for (int r = 0; r < 4; ++r) {
            int rloc = wr * 64 + m * 16 + lg * 4 + r;
            if (row0 + rloc < cnt) {
                int   tt = stok[rloc];
                float wgt = swt[rloc];
                float* orow = out + (long)tt * H_DIM + n0 + wc * 64;
#pragma unroll
                for (int n = 0; n < 4; ++n)
                    atomicAdd(&orow[n * 16 + lr], wgt * acc[m][n][r]);
            }
        }
}

// ---------------- launch ----------------------------------------------------
extern "C" void kernel_launch(void* const* d_in, const int* in_sizes, int n_in,
                              void* d_out, int out_size, void* d_ws, size_t ws_size,
                              hipStream_t stream)
{
    const float* x  = (const float*)d_in[0];
    const float* Wg = (const float*)d_in[1];
    const float* W1 = (const float*)d_in[2];
    const float* W2 = (const float*)d_in[3];
    float* out     = (float*)d_out;
    float* out_rl  = out + (size_t)T_TOK * H_DIM;
    float* out_aux = out_rl + (size_t)T_TOK * NE;

    char* ws = (char*)d_ws;
    int*    counts  = (int*)(ws + 0);
    double* accp    = (double*)(ws + 64);
    double* zsum    = (double*)(ws + 128);
    int*    offsets = (int*)(ws + 192);
    int*    toklist = (int*)(ws + 256);
    float*  wtlist  = (float*)(ws + 256 + 131072);
    // f16 regions (all 16B-aligned)
    const size_t XH_OFF = 262656;
    f16* xh = (f16*)(ws + XH_OFF);
    const size_t W_OFF = XH_OFF + (size_t)T_TOK * H_DIM * 2;  // 8651264

    // chunk FF so W1t + W2t + Hbuf fit:
    // bytes = 8*cf*1024*2 (W1t) + 8*1024*cf*2 (W2t) + HBUF_ROWS*cf*2
    int cf = FF_DIM;
    while (cf > 128 &&
           W_OFF + 32768ULL * cf + (unsigned long long)HBUF_ROWS * cf * 2 > ws_size)
        cf >>= 1;
    f16* W1t  = (f16*)(ws + W_OFF);
    f16* W2t  = W1t + (size_t)NE * cf * H_DIM;
    f16* Hbuf = W2t + (size_t)NE * H_DIM * cf;

    hipMemsetAsync(d_out, 0, (size_t)T_TOK * H_DIM * sizeof(float), stream);
    hipMemsetAsync(d_ws, 0, 256, stream);

    cvt_x_kernel<<<T_TOK * H_DIM / (8 * 256), 256, 0, stream>>>(x, xh);
    router_kernel<<<T_TOK, 64, 0, stream>>>(x, Wg, out_rl, counts, toklist, wtlist,
                                            accp, zsum);
    finalize_kernel<<<1, 64, 0, stream>>>(counts, offsets, accp, zsum, out_aux);

    int nchunks = FF_DIM / cf;
    for (int c = 0; c < nchunks; ++c) {
        long f0 = (long)c * cf;
        // W1 [1024 x FF] chunk cols [f0,f0+cf) -> W1t [cf x 1024]
        tr_kernel<<<dim3(cf / 32, H_DIM / 32, NE), 256, 0, stream>>>(
            W1 + f0, W1t, FF_DIM, H_DIM,
            (long)H_DIM * FF_DIM, (long)cf * H_DIM);
        // W2 [FF x 1024] chunk rows [f0,f0+cf) -> W2t [1024 x cf]
        tr_kernel<<<dim3(H_DIM / 32, cf / 32, NE), 256, 0, stream>>>(
            W2 + f0 * H_DIM, W2t, H_DIM, cf,
            (long)FF_DIM * H_DIM, (long)H_DIM * cf);

        gemm1_f16_kernel<<<dim3(cf / 128, CAP / 128, NE), 256, 0, stream>>>(
            xh, W1t, counts, offsets, toklist, Hbuf, cf);
        gemm2_f16_kernel<<<dim3(H_DIM / 128, CAP / 128, NE), 256, 0, stream>>>(
            Hbuf, W2t, counts, offsets, toklist, wtlist, out, cf);
    }
}

// Round 4
// 633.882 us; speedup vs baseline: 4.5624x; 1.6276x over previous
//
#include <hip/hip_runtime.h>
#include <math.h>

// MoE MLP (top-2 of 8), T=4096, H=1024, FF=4096.
// Round 4: fix router atomic serialization (435us -> ~25us predicted).
// Expert GEMMs stay on f16 MFMA (passed r3 at absmax 0.0078).

#define T_TOK 4096
#define H_DIM 1024
#define FF_DIM 4096
#define NE 8
#define CAP 4096
#define HBUF_ROWS (2 * T_TOK + 128)   // +128 rows slack: staging may read past cnt

typedef _Float16 f16;
typedef _Float16 f16x8 __attribute__((ext_vector_type(8)));
typedef _Float16 f16x4 __attribute__((ext_vector_type(4)));
typedef float    f32x4 __attribute__((ext_vector_type(4)));

__device__ __forceinline__ float gelu_tanh(float v) {
    const float c = 0.7978845608028654f;
    float u = c * (v + 0.044715f * v * v * v);
    return 0.5f * v * (1.0f + tanhf(u));
}

__device__ __forceinline__ void gload16(const void* g, void* l) {
    __builtin_amdgcn_global_load_lds(
        (const __attribute__((address_space(1))) unsigned int*)g,
        (__attribute__((address_space(3))) unsigned int*)l, 16, 0, 0);
}

// ---------------- logits: wave-per-token dot product, NO atomics ------------
__global__ __launch_bounds__(64) void logits_kernel(
    const float* __restrict__ x, const float* __restrict__ Wg,
    float* __restrict__ out_rl)
{
    int t = blockIdx.x;
    int lane = threadIdx.x;
    float acc[NE];
#pragma unroll
    for (int e = 0; e < NE; ++e) acc[e] = 0.f;
    const float* xr = x + (size_t)t * H_DIM;
    for (int h = lane; h < H_DIM; h += 64) {
        float xv = xr[h];
        const float4* wr = (const float4*)(Wg + (size_t)h * NE);
        float4 w0 = wr[0], w1 = wr[1];
        acc[0] += xv * w0.x; acc[1] += xv * w0.y;
        acc[2] += xv * w0.z; acc[3] += xv * w0.w;
        acc[4] += xv * w1.x; acc[5] += xv * w1.y;
        acc[6] += xv * w1.z; acc[7] += xv * w1.w;
    }
#pragma unroll
    for (int e = 0; e < NE; ++e) {
#pragma unroll
        for (int off = 32; off; off >>= 1) acc[e] += __shfl_xor(acc[e], off, 64);
    }
    if (lane != 0) return;
    float4* op = (float4*)(out_rl + (size_t)t * NE);
    op[0] = make_float4(acc[0], acc[1], acc[2], acc[3]);
    op[1] = make_float4(acc[4], acc[5], acc[6], acc[7]);
}

// ---------------- route: one thread per token, hierarchical reductions ------
// 16 blocks x 256 threads. accp/zsum: wave shfl -> LDS -> 9 f64 atomics/block.
// counts/toklist: 64-bit-ballot wave-aggregated atomics.
__global__ __launch_bounds__(256) void route_kernel(
    const float* __restrict__ out_rl, int* __restrict__ counts,
    int* __restrict__ toklist, float* __restrict__ wtlist,
    double* __restrict__ accp, double* __restrict__ zsum)
{
    __shared__ double red[4][9];
    int tid = threadIdx.x;
    int t = blockIdx.x * 256 + tid;
    int lane = tid & 63, wv = tid >> 6;

    float a[NE];
    float4 l0 = *(const float4*)(out_rl + (size_t)t * NE);
    float4 l1 = *(const float4*)(out_rl + (size_t)t * NE + 4);
    a[0] = l0.x; a[1] = l0.y; a[2] = l0.z; a[3] = l0.w;
    a[4] = l1.x; a[5] = l1.y; a[6] = l1.z; a[7] = l1.w;

    // top-2 (lowest index wins ties, matching lax.top_k)
    int i0 = 0; float v0 = a[0];
#pragma unroll
    for (int e = 1; e < NE; ++e) { if (a[e] > v0) { v0 = a[e]; i0 = e; } }
    int i1 = -1; float v1 = -3.4e38f;
#pragma unroll
    for (int e = 0; e < NE; ++e) {
        if (e == i0) continue;
        if (a[e] > v1) { v1 = a[e]; i1 = e; }
    }
    float ed = expf(v1 - v0);
    float rw0 = 1.f / (1.f + ed);
    float rw1 = ed / (1.f + ed);

    // softmax probs + logsumexp (per token)
    float s = 0.f, p[NE];
#pragma unroll
    for (int e = 0; e < NE; ++e) { p[e] = expf(a[e] - v0); s += p[e]; }
    float inv = 1.f / s;
    float lse = v0 + logf(s);

    double vals[9];
#pragma unroll
    for (int e = 0; e < NE; ++e) vals[e] = (double)(p[e] * inv);
    vals[8] = (double)lse * (double)lse;

    // wave reduce (64 lanes)
#pragma unroll
    for (int q = 0; q < 9; ++q) {
#pragma unroll
        for (int off = 32; off; off >>= 1) vals[q] += __shfl_xor(vals[q], off, 64);
    }
    if (lane == 0) {
#pragma unroll
        for (int q = 0; q < 9; ++q) red[wv][q] = vals[q];
    }
    __syncthreads();
    if (tid == 0) {
#pragma unroll
        for (int q = 0; q < 9; ++q) {
            double v = red[0][q] + red[1][q] + red[2][q] + red[3][q];
            if (q < 8) atomicAdd(&accp[q], v);
            else       atomicAdd(zsum, v);
        }
    }

    // wave-aggregated list construction (order within expert list is arbitrary)
#pragma unroll
    for (int e = 0; e < NE; ++e) {
#pragma unroll
        for (int k = 0; k < 2; ++k) {
            int pick = k ? i1 : i0;
            float rw = k ? rw1 : rw0;
            unsigned long long m = __ballot(pick == e);
            if (m) {
                int leader = (int)__builtin_ctzll(m);
                int base = 0;
                if (lane == leader) base = atomicAdd(&counts[e], (int)__popcll(m));
                base = __shfl(base, leader, 64);
                if (pick == e) {
                    int pos = base + (int)__popcll(m & ((1ull << lane) - 1ull));
                    toklist[e * CAP + pos] = t;
                    wtlist[e * CAP + pos] = rw;
                }
            }
        }
    }
}

__global__ void finalize_kernel(const int* __restrict__ counts, int* __restrict__ offsets,
                                const double* __restrict__ accp, const double* __restrict__ zsum,
                                float* __restrict__ out_aux)
{
    if (threadIdx.x == 0 && blockIdx.x == 0) {
        int off = 0;
        double psum = 0.0, sw = 0.0;
        int c[NE];
        for (int e = 0; e < NE; ++e) {
            c[e] = counts[e]; offsets[e] = off; off += c[e]; psum += accp[e];
        }
        for (int e = 0; e < NE; ++e)
            sw += (accp[e] / psum) * ((double)c[e] / (double)(T_TOK * 2));
        sw *= (double)NE;
        double z = zsum[0] / (double)T_TOK;
        out_aux[0] = (float)(sw + 0.1 * z);
    }
}

// ---------------- x -> f16 --------------------------------------------------
__global__ __launch_bounds__(256) void cvt_x_kernel(const float* __restrict__ x,
                                                    f16* __restrict__ xh)
{
    int i = (blockIdx.x * 256 + threadIdx.x) * 8;
    float4 a = *(const float4*)(x + i);
    float4 b = *(const float4*)(x + i + 4);
    f16x8 v = { (f16)a.x, (f16)a.y, (f16)a.z, (f16)a.w,
                (f16)b.x, (f16)b.y, (f16)b.z, (f16)b.w };
    *(f16x8*)(xh + i) = v;
}

// ---------------- fp32 [R][C] -> f16 [C][R] transpose (per expert z) --------
__global__ __launch_bounds__(256) void tr_kernel(
    const float* __restrict__ src, f16* __restrict__ dst,
    int src_ld, int dst_ld, long src_es, long dst_es)
{
    __shared__ f16 t[32 * 33];
    int e = blockIdx.z;
    src += (long)e * src_es; dst += (long)e * dst_es;
    int c0 = blockIdx.x * 32, r0 = blockIdx.y * 32;
    int tid = threadIdx.x;
    int cl = tid & 31, rl = tid >> 5;
#pragma unroll
    for (int i = 0; i < 4; ++i) {
        int r = rl + i * 8;
        t[cl * 33 + r] = (f16)src[(long)(r0 + r) * src_ld + c0 + cl];
    }
    __syncthreads();
    int cs = tid >> 3, r4 = (tid & 7) * 4;
    f16x4 v = { t[cs * 33 + r4], t[cs * 33 + r4 + 1],
                t[cs * 33 + r4 + 2], t[cs * 33 + r4 + 3] };
    *(f16x4*)(dst + (long)(c0 + cs) * dst_ld + r0 + r4) = v;
}

// ---------------- GEMM1: Hbuf = gelu(gather(xh) @ W1t^T) f16 MFMA -----------
__global__ __launch_bounds__(256) void gemm1_f16_kernel(
    const f16* __restrict__ xh, const f16* __restrict__ W1t,
    const int* __restrict__ counts, const int* __restrict__ offsets,
    const int* __restrict__ toklist, f16* __restrict__ Hbuf, int cf)
{
    int e = blockIdx.z;
    int cnt = counts[e];
    int row0 = blockIdx.y * 128;
    if (row0 >= cnt) return;
    int n0 = blockIdx.x * 128;

    __shared__ f16 lds[16384];           // A: [0,4096) B: [4096,8192); epilogue reuses all
    __shared__ int stok[128];
    f16* Ah = lds;
    f16* Bh = lds + 4096;

    int tid = threadIdx.x;
    if (tid < 128) {
        int r = row0 + tid;
        stok[tid] = (r < cnt) ? toklist[e * CAP + r] : 0;
    }
    __syncthreads();

    int l = tid & 63, w = tid >> 6;
    int wr = w >> 1, wc = w & 1;

    int sr = l >> 2;                 // staged row within 16-row group
    int sk = (l & 3) * 8;            // k offset (halves)
    int aR0 = w * 32 + sr, aR1 = aR0 + 16;
    const f16* aG0 = xh + (long)stok[aR0] * H_DIM + sk;
    const f16* aG1 = xh + (long)stok[aR1] * H_DIM + sk;
    const f16* bG0 = W1t + ((long)e * cf + n0 + aR0) * H_DIM + sk;
    const f16* bG1 = W1t + ((long)e * cf + n0 + aR1) * H_DIM + sk;
    f16* aL = Ah + w * 1024;         // wave-uniform LDS dest bases
    f16* bL = Bh + w * 1024;

    f32x4 acc[4][4];
#pragma unroll
    for (int m = 0; m < 4; ++m)
#pragma unroll
        for (int n = 0; n < 4; ++n) acc[m][n] = (f32x4){0.f, 0.f, 0.f, 0.f};

    int lr = l & 15, lg = l >> 4;
    for (int k0 = 0; k0 < H_DIM; k0 += 32) {
        __syncthreads();
        gload16(aG0 + k0, aL);
        gload16(aG1 + k0, aL + 512);
        gload16(bG0 + k0, bL);
        gload16(bG1 + k0, bL + 512);
        __syncthreads();
        f16x8 af[4], bf[4];
#pragma unroll
        for (int m = 0; m < 4; ++m)
            af[m] = *(const f16x8*)&Ah[(wr * 64 + m * 16 + lr) * 32 + lg * 8];
#pragma unroll
        for (int n = 0; n < 4; ++n)
            bf[n] = *(const f16x8*)&Bh[(wc * 64 + n * 16 + lr) * 32 + lg * 8];
#pragma unroll
        for (int m = 0; m < 4; ++m)
#pragma unroll
            for (int n = 0; n < 4; ++n)
                acc[m][n] = __builtin_amdgcn_mfma_f32_16x16x32_f16(af[m], bf[n], acc[m][n], 0, 0, 0);
    }

    // epilogue: gelu -> f16 via LDS bounce, vectorized stores
    __syncthreads();
    int obase = offsets[e];
    f16* ct = lds + w * 4096;        // 64x64 halves per wave
#pragma unroll
    for (int m = 0; m < 4; ++m)
#pragma unroll
        for (int n = 0; n < 4; ++n)
#pragma unroll
            for (int r = 0; r < 4; ++r)
                ct[(m * 16 + lg * 4 + r) * 64 + n * 16 + lr] = (f16)gelu_tanh(acc[m][n][r]);
#pragma unroll
    for (int i = 0; i < 8; ++i) {
        int rr = i * 8 + (l >> 3);
        int grow = row0 + wr * 64 + rr;
        if (grow < cnt) {
            f16x8 v = *(const f16x8*)&ct[rr * 64 + (l & 7) * 8];
            *(f16x8*)(Hbuf + (long)(obase + grow) * cf + n0 + wc * 64 + (l & 7) * 8) = v;
        }
    }
}

// ---------------- GEMM2: out += w * (Hbuf @ W2t^T), scatter atomics ---------
__global__ __launch_bounds__(256) void gemm2_f16_kernel(
    const f16* __restrict__ Hbuf, const f16* __restrict__ W2t,
    const int* __restrict__ counts, const int* __restrict__ offsets,
    const int* __restrict__ toklist, const float* __restrict__ wtlist,
    float* __restrict__ out, int cf)
{
    int e = blockIdx.z;
    int cnt = counts[e];
    int row0 = blockIdx.y * 128;
    if (row0 >= cnt) return;
    int n0 = blockIdx.x * 128;

    __shared__ f16 lds[8192];            // A: [0,4096) B: [4096,8192)
    __shared__ int   stok[128];
    __shared__ float swt[128];
    f16* Ah = lds;
    f16* Bh = lds + 4096;

    int tid = threadIdx.x;
    if (tid < 128) {
        int r = row0 + tid;
        stok[tid] = (r < cnt) ? toklist[e * CAP + r] : 0;
        swt[tid]  = (r < cnt) ? wtlist[e * CAP + r] : 0.f;
    }
    __syncthreads();

    int l = tid & 63, w = tid >> 6;
    int wr = w >> 1, wc = w & 1;

    int sr = l >> 2;
    int sk = (l & 3) * 8;
    int aR0 = w * 32 + sr, aR1 = aR0 + 16;
    int obase = offsets[e];
    // rows >= cnt read Hbuf slack rows (finite garbage, results discarded)
    const f16* aG0 = Hbuf + (long)(obase + row0 + aR0) * cf + sk;
    const f16* aG1 = Hbuf + (long)(obase + row0 + aR1) * cf + sk;
    const f16* bG0 = W2t + ((long)e * H_DIM + n0 + aR0) * cf + sk;
    const f16* bG1 = W2t + ((long)e * H_DIM + n0 + aR1) * cf + sk;
    f16* aL = Ah + w * 1024;
    f16* bL = Bh + w * 1024;

    f32x4 acc[4][4];
#pragma unroll
    for (int m = 0; m < 4; ++m)
#pragma unroll
        for (int n = 0; n < 4; ++n) acc[m][n] = (f32x4){0.f, 0.f, 0.f, 0.f};

    int lr = l & 15, lg = l >> 4;
    for (int k0 = 0; k0 < cf; k0 += 32) {
        __syncthreads();
        gload16(aG0 + k0, aL);
        gload16(aG1 + k0, aL + 512);
        gload16(bG0 + k0, bL);
        gload16(bG1 + k0, bL + 512);
        __syncthreads();
        f16x8 af[4], bf[4];
#pragma unroll
        for (int m = 0; m < 4; ++m)
            af[m] = *(const f16x8*)&Ah[(wr * 64 + m * 16 + lr) * 32 + lg * 8];
#pragma unroll
        for (int n = 0; n < 4; ++n)
            bf[n] = *(const f16x8*)&Bh[(wc * 64 + n * 16 + lr) * 32 + lg * 8];
#pragma unroll
        for (int m = 0; m < 4; ++m)
#pragma unroll
            for (int n = 0; n < 4; ++n)
                acc[m][n] = __builtin_amdgcn_mfma_f32_16x16x32_f16(af[m], bf[n], acc[m][n], 0, 0, 0);
    }

#pragma unroll
    for (int m = 0; m < 4; ++m)
#pragma unroll
        for (int r = 0; r < 4; ++r) {
            int rloc = wr * 64 + m * 16 + lg * 4 + r;
            if (row0 + rloc < cnt) {
                int   tt = stok[rloc];
                float wgt = swt[rloc];
                float* orow = out + (long)tt * H_DIM + n0 + wc * 64;
#pragma unroll
                for (int n = 0; n < 4; ++n)
                    atomicAdd(&orow[n * 16 + lr], wgt * acc[m][n][r]);
            }
        }
}

// ---------------- launch ----------------------------------------------------
extern "C" void kernel_launch(void* const* d_in, const int* in_sizes, int n_in,
                              void* d_out, int out_size, void* d_ws, size_t ws_size,
                              hipStream_t stream)
{
    const float* x  = (const float*)d_in[0];
    const float* Wg = (const float*)d_in[1];
    const float* W1 = (const float*)d_in[2];
    const float* W2 = (const float*)d_in[3];
    float* out     = (float*)d_out;
    float* out_rl  = out + (size_t)T_TOK * H_DIM;
    float* out_aux = out_rl + (size_t)T_TOK * NE;

    char* ws = (char*)d_ws;
    int*    counts  = (int*)(ws + 0);
    double* accp    = (double*)(ws + 64);
    double* zsum    = (double*)(ws + 128);
    int*    offsets = (int*)(ws + 192);
    int*    toklist = (int*)(ws + 256);
    float*  wtlist  = (float*)(ws + 256 + 131072);
    const size_t XH_OFF = 262656;
    f16* xh = (f16*)(ws + XH_OFF);
    const size_t W_OFF = XH_OFF + (size_t)T_TOK * H_DIM * 2;  // 8651264

    int cf = FF_DIM;
    while (cf > 128 &&
           W_OFF + 32768ULL * cf + (unsigned long long)HBUF_ROWS * cf * 2 > ws_size)
        cf >>= 1;
    f16* W1t  = (f16*)(ws + W_OFF);
    f16* W2t  = W1t + (size_t)NE * cf * H_DIM;
    f16* Hbuf = W2t + (size_t)NE * H_DIM * cf;

    hipMemsetAsync(d_out, 0, (size_t)T_TOK * H_DIM * sizeof(float), stream);
    hipMemsetAsync(d_ws, 0, 256, stream);

    cvt_x_kernel<<<T_TOK * H_DIM / (8 * 256), 256, 0, stream>>>(x, xh);
    logits_kernel<<<T_TOK, 64, 0, stream>>>(x, Wg, out_rl);
    route_kernel<<<T_TOK / 256, 256, 0, stream>>>(out_rl, counts, toklist, wtlist,
                                                  accp, zsum);
    finalize_kernel<<<1, 64, 0, stream>>>(counts, offsets, accp, zsum, out_aux);

    int nchunks = FF_DIM / cf;
    for (int c = 0; c < nchunks; ++c) {
        long f0 = (long)c * cf;
        tr_kernel<<<dim3(cf / 32, H_DIM / 32, NE), 256, 0, stream>>>(
            W1 + f0, W1t, FF_DIM, H_DIM,
            (long)H_DIM * FF_DIM, (long)cf * H_DIM);
        tr_kernel<<<dim3(H_DIM / 32, cf / 32, NE), 256, 0, stream>>>(
            W2 + f0 * H_DIM, W2t, H_DIM, cf,
            (long)FF_DIM * H_DIM, (long)H_DIM * cf);

        gemm1_f16_kernel<<<dim3(cf / 128, CAP / 128, NE), 256, 0, stream>>>(
            xh, W1t, counts, offsets, toklist, Hbuf, cf);
        gemm2_f16_kernel<<<dim3(H_DIM / 128, CAP / 128, NE), 256, 0, stream>>>(
            Hbuf, W2t, counts, offsets, toklist, wtlist, out, cf);
    }
}